// Round 1
// baseline (430.869 us; speedup 1.0000x reference)
//
#include <hip/hip_runtime.h>
#include <math.h>

#define B_ 8
#define S_ 4096
#define D_ 1024
#define N_ 64
#define SHIFT_ 2048
#define LCH 32
#define CCH 128            // S_/LCH
#define MTOT (B_*S_)
#define EPS_ 1e-5f

// ---------------- K0: sigmoid of time_shift_gates ----------------
__global__ __launch_bounds__(256) void k_gate(const float* __restrict__ tsg,
                                              float* __restrict__ g) {
    int i = blockIdx.x * 256 + threadIdx.x;
    if (i < D_) g[i] = 1.0f / (1.0f + __expf(-tsg[i]));
}

// ---------------- K1: shift + LN stats (pair trick: rows t and t+2048) -----
__global__ __launch_bounds__(256) void k_stats(const float* __restrict__ x,
                                               const float* __restrict__ g,
                                               float* __restrict__ mu,
                                               float* __restrict__ rstd) {
    int b = blockIdx.x >> 11;       // /2048
    int t = blockIdx.x & 2047;
    const float* rowa = x + ((size_t)(b * S_ + t)) * D_;
    const float* rowb = rowa + (size_t)SHIFT_ * D_;
    int c = threadIdx.x * 4;
    float4 xa = *(const float4*)(rowa + c);
    float4 xb = *(const float4*)(rowb + c);
    float4 gg = *(const float4*)(g + c);
    float av[4] = {xa.x, xa.y, xa.z, xa.w};
    float bv[4] = {xb.x, xb.y, xb.z, xb.w};
    float gv[4] = {gg.x, gg.y, gg.z, gg.w};
    float s1 = 0.f, q1 = 0.f, s2 = 0.f, q2 = 0.f;
#pragma unroll
    for (int j = 0; j < 4; j++) {
        // token t:      x_cat = x[t+2048]
        float u  = gv[j] * bv[j] + (1.f - gv[j]) * av[j];
        // token t+2048: x_cat = x[t]
        float w2 = gv[j] * av[j] + (1.f - gv[j]) * bv[j];
        s1 += u;  q1 += u * u;
        s2 += w2; q2 += w2 * w2;
    }
    __shared__ float red[4][4];
    int lane = threadIdx.x & 63, wv = threadIdx.x >> 6;
#pragma unroll
    for (int off = 32; off > 0; off >>= 1) {
        s1 += __shfl_down(s1, off);
        q1 += __shfl_down(q1, off);
        s2 += __shfl_down(s2, off);
        q2 += __shfl_down(q2, off);
    }
    if (lane == 0) { red[wv][0] = s1; red[wv][1] = q1; red[wv][2] = s2; red[wv][3] = q2; }
    __syncthreads();
    if (threadIdx.x == 0) {
        float S1 = 0, Q1 = 0, S2 = 0, Q2 = 0;
#pragma unroll
        for (int i = 0; i < 4; i++) { S1 += red[i][0]; Q1 += red[i][1]; S2 += red[i][2]; Q2 += red[i][3]; }
        float m1 = S1 * (1.f / D_), m2 = S2 * (1.f / D_);
        float v1 = Q1 * (1.f / D_) - m1 * m1;
        float v2 = Q2 * (1.f / D_) - m2 * m2;
        int m = b * S_ + t;
        mu[m] = m1;           rstd[m] = rsqrtf(v1 + EPS_);
        mu[m + SHIFT_] = m2;  rstd[m + SHIFT_] = rsqrtf(v2 + EPS_);
    }
}

// ---------------- K2: fused shift+LN+K/V projection + wkv epilogue --------
// GEMM: (64 tokens) x (128 outs: 64 k | 64 v), K=1024, BK=32
__global__ __launch_bounds__(256) void k_proj(
    const float* __restrict__ x, const float* __restrict__ keyw,
    const float* __restrict__ valw, const float* __restrict__ g,
    const float* __restrict__ lnw, const float* __restrict__ lnb,
    const float* __restrict__ tf, const float* __restrict__ mu,
    const float* __restrict__ rstd, float* __restrict__ wkv) {
    __shared__ float smem[64 * 132];       // 33.8 KB, aliased
    float* As = smem;                      // [64][36]
    float* Bs = smem + 64 * 36;            // [32][132]

    int m0 = blockIdx.x * 64;
    int b = m0 >> 12;
    int t0 = m0 & 4095;
    int t2 = (t0 + SHIFT_) & 4095;
    const float* xa_base = x + ((size_t)(b * S_ + t0)) * D_;
    const float* xb_base = x + ((size_t)(b * S_ + t2)) * D_;

    int tid = threadIdx.x;
    int ty = tid >> 4, tx = tid & 15;
    int tokA = tid >> 3;
    int cA = (tid & 7) * 4;

    float mu0 = mu[m0 + tokA],      rs0 = rstd[m0 + tokA];
    float mu1 = mu[m0 + tokA + 32], rs1 = rstd[m0 + tokA + 32];

    int nB = tid >> 1;
    int halfB = tid & 1;
    const float* wrow = (nB < 64) ? (keyw + (size_t)nB * D_)
                                  : (valw + (size_t)(nB - 64) * D_);

    float acc[4][8];
#pragma unroll
    for (int i = 0; i < 4; i++)
#pragma unroll
        for (int j = 0; j < 8; j++) acc[i][j] = 0.f;

    for (int kk0 = 0; kk0 < D_; kk0 += 32) {
        // ---- stage A (shift + LN on the fly) ----
        float4 gg = *(const float4*)(g + kk0 + cA);
        float4 lw = *(const float4*)(lnw + kk0 + cA);
        float4 lb = *(const float4*)(lnb + kk0 + cA);
        float gv[4] = {gg.x, gg.y, gg.z, gg.w};
        float lwv[4] = {lw.x, lw.y, lw.z, lw.w};
        float lbv[4] = {lb.x, lb.y, lb.z, lb.w};
#pragma unroll
        for (int r = 0; r < 2; r++) {
            int tok = tokA + r * 32;
            float4 xa = *(const float4*)(xa_base + (size_t)tok * D_ + kk0 + cA);
            float4 xb = *(const float4*)(xb_base + (size_t)tok * D_ + kk0 + cA);
            float xav[4] = {xa.x, xa.y, xa.z, xa.w};
            float xbv[4] = {xb.x, xb.y, xb.z, xb.w};
            float m_ = r ? mu1 : mu0;
            float rs_ = r ? rs1 : rs0;
#pragma unroll
            for (int j = 0; j < 4; j++) {
                float xs = gv[j] * xbv[j] + (1.f - gv[j]) * xav[j];
                As[tok * 36 + cA + j] = (xs - m_) * rs_ * lwv[j] + lbv[j];
            }
        }
        // ---- stage B (transpose into [BK][128+4]) ----
#pragma unroll
        for (int cc = 0; cc < 16; cc += 4) {
            int kk = halfB * 16 + cc;
            float4 wv4 = *(const float4*)(wrow + kk0 + kk);
            Bs[(kk + 0) * 132 + nB] = wv4.x;
            Bs[(kk + 1) * 132 + nB] = wv4.y;
            Bs[(kk + 2) * 132 + nB] = wv4.z;
            Bs[(kk + 3) * 132 + nB] = wv4.w;
        }
        __syncthreads();
#pragma unroll
        for (int kk = 0; kk < 32; kk++) {
            float a0 = As[(ty * 4 + 0) * 36 + kk];
            float a1 = As[(ty * 4 + 1) * 36 + kk];
            float a2 = As[(ty * 4 + 2) * 36 + kk];
            float a3 = As[(ty * 4 + 3) * 36 + kk];
            float bvv[8];
#pragma unroll
            for (int j = 0; j < 8; j++) bvv[j] = Bs[kk * 132 + tx * 8 + j];
#pragma unroll
            for (int j = 0; j < 8; j++) {
                acc[0][j] = fmaf(a0, bvv[j], acc[0][j]);
                acc[1][j] = fmaf(a1, bvv[j], acc[1][j]);
                acc[2][j] = fmaf(a2, bvv[j], acc[2][j]);
                acc[3][j] = fmaf(a3, bvv[j], acc[3][j]);
            }
        }
        __syncthreads();
    }
    // ---- epilogue: pair k/v, compute wkv ----
#pragma unroll
    for (int i = 0; i < 4; i++)
#pragma unroll
        for (int j = 0; j < 8; j++)
            smem[(ty * 4 + i) * 132 + tx * 8 + j] = acc[i][j];
    __syncthreads();
    {
        int tok = tid >> 2;
        int n0 = (tid & 3) * 16;
        float* orow = wkv + ((size_t)(m0 + tok)) * N_ + n0;
#pragma unroll
        for (int jj = 0; jj < 16; jj++) {
            int n = n0 + jj;
            float kv = smem[tok * 132 + n];
            float vv = smem[tok * 132 + 64 + n];
            orow[jj] = __expf(-__expf(tf[n]) * kv) * vv;
        }
    }
}

// ---------------- K3: per-chunk local scan -> chunk carries ----------------
__global__ __launch_bounds__(64) void k_chunk(const float* __restrict__ wkv,
                                              const float* __restrict__ tdec,
                                              float* __restrict__ Acar) {
    int idx = blockIdx.x;            // b*CCH + c
    int n = threadIdx.x;
    float w = expf(tdec[n]);
    const float* p = wkv + (size_t)idx * (LCH * N_) + n;
    float s = 0.f;
#pragma unroll
    for (int i = 0; i < LCH; i++) s = s * w + p[i * N_];
    Acar[idx * N_ + n] = s;
}

// ---------------- K4: scan carries across chunks; write last_states -------
__global__ __launch_bounds__(64) void k_carry(const float* __restrict__ Acar,
                                              const float* __restrict__ tdec,
                                              float* __restrict__ Cin,
                                              float* __restrict__ last) {
    int b = blockIdx.x;
    int n = threadIdx.x;
    float wL = expf(tdec[n] * (float)LCH);
    float c = 0.f;
    for (int ch = 0; ch < CCH; ch++) {
        Cin[(b * CCH + ch) * N_ + n] = c;
        c = c * wL + Acar[(b * CCH + ch) * N_ + n];
    }
    last[b * N_ + n] = c;
}

// ---------------- K5: rescan chunks with carry-in -> exact states ----------
__global__ __launch_bounds__(64) void k_rescan(const float* __restrict__ wkv,
                                               const float* __restrict__ Cin,
                                               const float* __restrict__ tdec,
                                               float* __restrict__ st) {
    int idx = blockIdx.x;
    int n = threadIdx.x;
    float w = expf(tdec[n]);
    float s = Cin[idx * N_ + n];
    const float* p = wkv + (size_t)idx * (LCH * N_) + n;
    float* q = st + (size_t)idx * (LCH * N_) + n;
#pragma unroll
    for (int i = 0; i < LCH; i++) { s = s * w + p[i * N_]; q[i * N_] = s; }
}

// ---------------- K6: output projection GEMM -------------------------------
// (64 tokens) x (128 d), K=64 (BK=32 x2)
__global__ __launch_bounds__(256) void k_out(const float* __restrict__ st,
                                             const float* __restrict__ ow,
                                             float* __restrict__ out) {
    __shared__ float smem[64 * 36 + 32 * 132];
    float* As = smem;                // [64][36]
    float* Bs = smem + 64 * 36;      // [32][132]
    int m0 = (blockIdx.x >> 3) * 64;
    int d0 = (blockIdx.x & 7) * 128;
    int tid = threadIdx.x;
    int ty = tid >> 4, tx = tid & 15;
    int tokA = tid >> 3;
    int cA = (tid & 7) * 4;
    int ddB = tid >> 1;
    int halfB = tid & 1;
    float acc[4][8];
#pragma unroll
    for (int i = 0; i < 4; i++)
#pragma unroll
        for (int j = 0; j < 8; j++) acc[i][j] = 0.f;

    for (int kk0 = 0; kk0 < N_; kk0 += 32) {
#pragma unroll
        for (int r = 0; r < 2; r++) {
            int tok = tokA + r * 32;
            float4 v = *(const float4*)(st + ((size_t)(m0 + tok)) * N_ + kk0 + cA);
            As[tok * 36 + cA + 0] = v.x;
            As[tok * 36 + cA + 1] = v.y;
            As[tok * 36 + cA + 2] = v.z;
            As[tok * 36 + cA + 3] = v.w;
        }
        const float* wr = ow + (size_t)(d0 + ddB) * N_ + kk0;
#pragma unroll
        for (int cc = 0; cc < 16; cc += 4) {
            int kk = halfB * 16 + cc;
            float4 wv4 = *(const float4*)(wr + kk);
            Bs[(kk + 0) * 132 + ddB] = wv4.x;
            Bs[(kk + 1) * 132 + ddB] = wv4.y;
            Bs[(kk + 2) * 132 + ddB] = wv4.z;
            Bs[(kk + 3) * 132 + ddB] = wv4.w;
        }
        __syncthreads();
#pragma unroll
        for (int kk = 0; kk < 32; kk++) {
            float a0 = As[(ty * 4 + 0) * 36 + kk];
            float a1 = As[(ty * 4 + 1) * 36 + kk];
            float a2 = As[(ty * 4 + 2) * 36 + kk];
            float a3 = As[(ty * 4 + 3) * 36 + kk];
            float bvv[8];
#pragma unroll
            for (int j = 0; j < 8; j++) bvv[j] = Bs[kk * 132 + tx * 8 + j];
#pragma unroll
            for (int j = 0; j < 8; j++) {
                acc[0][j] = fmaf(a0, bvv[j], acc[0][j]);
                acc[1][j] = fmaf(a1, bvv[j], acc[1][j]);
                acc[2][j] = fmaf(a2, bvv[j], acc[2][j]);
                acc[3][j] = fmaf(a3, bvv[j], acc[3][j]);
            }
        }
        __syncthreads();
    }
#pragma unroll
    for (int i = 0; i < 4; i++) {
        float4 o0 = make_float4(acc[i][0], acc[i][1], acc[i][2], acc[i][3]);
        float4 o1 = make_float4(acc[i][4], acc[i][5], acc[i][6], acc[i][7]);
        float* orow = out + ((size_t)(m0 + ty * 4 + i)) * D_ + d0 + tx * 8;
        *(float4*)(orow) = o0;
        *(float4*)(orow + 4) = o1;
    }
}

extern "C" void kernel_launch(void* const* d_in, const int* in_sizes, int n_in,
                              void* d_out, int out_size, void* d_ws, size_t ws_size,
                              hipStream_t stream) {
    const float* x    = (const float*)d_in[0];
    const float* tdec = (const float*)d_in[1];
    const float* tf   = (const float*)d_in[2];
    const float* keyw = (const float*)d_in[3];
    const float* valw = (const float*)d_in[4];
    const float* ow   = (const float*)d_in[5];
    const float* tsg  = (const float*)d_in[6];
    const float* lnw  = (const float*)d_in[7];
    const float* lnb  = (const float*)d_in[8];
    float* out = (float*)d_out;
    float* ws  = (float*)d_ws;

    float* g    = ws;                  // 1024
    float* mu   = g + 1024;            // 32768
    float* rstd = mu + 32768;          // 32768
    float* wkv  = rstd + 32768;        // 2097152
    float* Acar = wkv + 2097152;       // 65536
    float* Cin  = Acar + 65536;        // 65536
    float* st   = Cin + 65536;         // 2097152  (total ~17.6 MB)

    k_gate  <<<4, 256, 0, stream>>>(tsg, g);
    k_stats <<<B_ * (S_ / 2), 256, 0, stream>>>(x, g, mu, rstd);
    k_proj  <<<MTOT / 64, 256, 0, stream>>>(x, keyw, valw, g, lnw, lnb, tf, mu, rstd, wkv);
    k_chunk <<<B_ * CCH, 64, 0, stream>>>(wkv, tdec, Acar);
    k_carry <<<B_, 64, 0, stream>>>(Acar, tdec, Cin, out + (size_t)MTOT * D_);
    k_rescan<<<B_ * CCH, 64, 0, stream>>>(wkv, Cin, tdec, st);
    k_out   <<<(MTOT / 64) * 8, 256, 0, stream>>>(st, ow, out);
}

// Round 2
// 322.032 us; speedup vs baseline: 1.3380x; 1.3380x over previous
//
#include <hip/hip_runtime.h>
#include <math.h>

#define B_ 8
#define S_ 4096
#define D_ 1024
#define N_ 64
#define SHIFT_ 2048
#define LCH 32
#define CCH 128            // S_/LCH
#define MTOT (B_*S_)
#define EPS_ 1e-5f

typedef __attribute__((ext_vector_type(8))) short v8s;
typedef __attribute__((ext_vector_type(4))) float v4f;

static __device__ __forceinline__ short f2bf(float f) {
    // round-to-nearest-even fp32 -> bf16
    unsigned int u = __float_as_uint(f);
    u += 0x7fffu + ((u >> 16) & 1u);
    return (short)(u >> 16);
}

// ---------------- k_conv: weights->bf16, exp(tf), sigmoid(gates) ----------
__global__ __launch_bounds__(256) void k_conv(
    const float* __restrict__ keyw, const float* __restrict__ valw,
    const float* __restrict__ ow, const float* __restrict__ tf,
    const float* __restrict__ tsg,
    short* __restrict__ wbf, short* __restrict__ owbf,
    float* __restrict__ etf, float* __restrict__ g) {
    int i = blockIdx.x * 256 + threadIdx.x;
    if (i < 65536)          wbf[i] = f2bf(keyw[i]);
    else if (i < 131072)    wbf[i] = f2bf(valw[i - 65536]);
    else if (i < 196608)    owbf[i - 131072] = f2bf(ow[i - 131072]);
    else if (i < 196672)    etf[i - 196608] = __expf(tf[i - 196608]);
    else if (i < 197696) {
        int j = i - 196672;
        g[j] = 1.0f / (1.0f + __expf(-tsg[j]));
    }
}

// ---------------- PRIMARY: shift + full LN -> bf16 x_norm ------------------
__global__ __launch_bounds__(256) void k_stats_fused(
    const float* __restrict__ x, const float* __restrict__ g,
    const float* __restrict__ lnw, const float* __restrict__ lnb,
    short* __restrict__ xn) {
    int b = blockIdx.x >> 11;
    int t = blockIdx.x & 2047;
    const float* rowa = x + ((size_t)(b * S_ + t)) * D_;
    const float* rowb = rowa + (size_t)SHIFT_ * D_;
    int c = threadIdx.x * 4;
    float4 xa = *(const float4*)(rowa + c);
    float4 xb = *(const float4*)(rowb + c);
    float4 gg = *(const float4*)(g + c);
    float av[4] = {xa.x, xa.y, xa.z, xa.w};
    float bv[4] = {xb.x, xb.y, xb.z, xb.w};
    float gv[4] = {gg.x, gg.y, gg.z, gg.w};
    float u[4], w2[4];
    float s1 = 0.f, q1 = 0.f, s2 = 0.f, q2 = 0.f;
#pragma unroll
    for (int j = 0; j < 4; j++) {
        u[j]  = gv[j] * bv[j] + (1.f - gv[j]) * av[j];   // token t
        w2[j] = gv[j] * av[j] + (1.f - gv[j]) * bv[j];   // token t+2048
        s1 += u[j];  q1 += u[j] * u[j];
        s2 += w2[j]; q2 += w2[j] * w2[j];
    }
    __shared__ float red[4][4];
    int lane = threadIdx.x & 63, wv = threadIdx.x >> 6;
#pragma unroll
    for (int off = 32; off > 0; off >>= 1) {
        s1 += __shfl_down(s1, off);
        q1 += __shfl_down(q1, off);
        s2 += __shfl_down(s2, off);
        q2 += __shfl_down(q2, off);
    }
    if (lane == 0) { red[wv][0] = s1; red[wv][1] = q1; red[wv][2] = s2; red[wv][3] = q2; }
    __syncthreads();
    float S1 = red[0][0] + red[1][0] + red[2][0] + red[3][0];
    float Q1 = red[0][1] + red[1][1] + red[2][1] + red[3][1];
    float S2 = red[0][2] + red[1][2] + red[2][2] + red[3][2];
    float Q2 = red[0][3] + red[1][3] + red[2][3] + red[3][3];
    float m1 = S1 * (1.f / D_), m2 = S2 * (1.f / D_);
    float rs1 = rsqrtf(Q1 * (1.f / D_) - m1 * m1 + EPS_);
    float rs2 = rsqrtf(Q2 * (1.f / D_) - m2 * m2 + EPS_);
    float4 lw = *(const float4*)(lnw + c);
    float4 lb = *(const float4*)(lnb + c);
    float lwv[4] = {lw.x, lw.y, lw.z, lw.w};
    float lbv[4] = {lb.x, lb.y, lb.z, lb.w};
    short o1[4], o2[4];
#pragma unroll
    for (int j = 0; j < 4; j++) {
        o1[j] = f2bf((u[j]  - m1) * rs1 * lwv[j] + lbv[j]);
        o2[j] = f2bf((w2[j] - m2) * rs2 * lwv[j] + lbv[j]);
    }
    short* d1 = xn + ((size_t)(b * S_ + t)) * D_ + c;
    short* d2 = d1 + (size_t)SHIFT_ * D_;
    *(short4*)d1 = make_short4(o1[0], o1[1], o1[2], o1[3]);
    *(short4*)d2 = make_short4(o2[0], o2[1], o2[2], o2[3]);
}

// ---------------- PRIMARY: MFMA K/V projection + wkv epilogue --------------
// C[64 tok][128 outs] = xnorm(64x1024) @ wbf^T ; no LDS in K-loop.
__global__ __launch_bounds__(256) void k_proj_mx(
    const short* __restrict__ xn, const short* __restrict__ wbf,
    const float* __restrict__ etf, float* __restrict__ wkv) {
    __shared__ float C[64 * 132];   // epilogue only (33.8 KB)
    int tid = threadIdx.x, wid = tid >> 6, lane = tid & 63;
    int wm = wid >> 1, wn = wid & 1;
    int quad = lane >> 4, l15 = lane & 15;
    int m0 = blockIdx.x * 64;
    const short* ab = xn + ((size_t)(m0 + wm * 32 + l15)) * D_ + quad * 8;
    const short* bb = wbf + ((size_t)(wn * 64 + l15)) * D_ + quad * 8;
    v4f acc[2][4];
#pragma unroll
    for (int i = 0; i < 2; i++)
#pragma unroll
        for (int j = 0; j < 4; j++) acc[i][j] = (v4f)0.f;

#pragma unroll 4
    for (int k0 = 0; k0 < D_; k0 += 32) {
        v8s a0 = *(const v8s*)(ab + k0);
        v8s a1 = *(const v8s*)(ab + (size_t)16 * D_ + k0);
        v8s b0 = *(const v8s*)(bb + k0);
        v8s b1 = *(const v8s*)(bb + (size_t)16 * D_ + k0);
        v8s b2 = *(const v8s*)(bb + (size_t)32 * D_ + k0);
        v8s b3 = *(const v8s*)(bb + (size_t)48 * D_ + k0);
        acc[0][0] = __builtin_amdgcn_mfma_f32_16x16x32_bf16(a0, b0, acc[0][0], 0, 0, 0);
        acc[0][1] = __builtin_amdgcn_mfma_f32_16x16x32_bf16(a0, b1, acc[0][1], 0, 0, 0);
        acc[0][2] = __builtin_amdgcn_mfma_f32_16x16x32_bf16(a0, b2, acc[0][2], 0, 0, 0);
        acc[0][3] = __builtin_amdgcn_mfma_f32_16x16x32_bf16(a0, b3, acc[0][3], 0, 0, 0);
        acc[1][0] = __builtin_amdgcn_mfma_f32_16x16x32_bf16(a1, b0, acc[1][0], 0, 0, 0);
        acc[1][1] = __builtin_amdgcn_mfma_f32_16x16x32_bf16(a1, b1, acc[1][1], 0, 0, 0);
        acc[1][2] = __builtin_amdgcn_mfma_f32_16x16x32_bf16(a1, b2, acc[1][2], 0, 0, 0);
        acc[1][3] = __builtin_amdgcn_mfma_f32_16x16x32_bf16(a1, b3, acc[1][3], 0, 0, 0);
    }
    // C/D layout: col = lane&15, row = quad*4 + reg
#pragma unroll
    for (int i = 0; i < 2; i++)
#pragma unroll
        for (int j = 0; j < 4; j++)
#pragma unroll
            for (int r = 0; r < 4; r++)
                C[(wm * 32 + i * 16 + quad * 4 + r) * 132 + wn * 64 + j * 16 + l15] = acc[i][j][r];
    __syncthreads();
    int tok = tid >> 2, n0 = (tid & 3) * 16;
    float* orow = wkv + ((size_t)(m0 + tok)) * N_ + n0;
#pragma unroll
    for (int jj = 0; jj < 16; jj += 4) {
        float4 o;
        float* pk = &C[tok * 132 + n0 + jj];
        float* pv = &C[tok * 132 + 64 + n0 + jj];
        o.x = __expf(-etf[n0 + jj + 0] * pk[0]) * pv[0];
        o.y = __expf(-etf[n0 + jj + 1] * pk[1]) * pv[1];
        o.z = __expf(-etf[n0 + jj + 2] * pk[2]) * pv[2];
        o.w = __expf(-etf[n0 + jj + 3] * pk[3]) * pv[3];
        *(float4*)(orow + jj) = o;
    }
}

// ---------------- FALLBACK: LN stats only ----------------------------------
__global__ __launch_bounds__(256) void k_stats_mu(const float* __restrict__ x,
                                                  const float* __restrict__ g,
                                                  float* __restrict__ mu,
                                                  float* __restrict__ rstd) {
    int b = blockIdx.x >> 11;
    int t = blockIdx.x & 2047;
    const float* rowa = x + ((size_t)(b * S_ + t)) * D_;
    const float* rowb = rowa + (size_t)SHIFT_ * D_;
    int c = threadIdx.x * 4;
    float4 xa = *(const float4*)(rowa + c);
    float4 xb = *(const float4*)(rowb + c);
    float4 gg = *(const float4*)(g + c);
    float av[4] = {xa.x, xa.y, xa.z, xa.w};
    float bv[4] = {xb.x, xb.y, xb.z, xb.w};
    float gv[4] = {gg.x, gg.y, gg.z, gg.w};
    float s1 = 0.f, q1 = 0.f, s2 = 0.f, q2 = 0.f;
#pragma unroll
    for (int j = 0; j < 4; j++) {
        float u  = gv[j] * bv[j] + (1.f - gv[j]) * av[j];
        float w2 = gv[j] * av[j] + (1.f - gv[j]) * bv[j];
        s1 += u;  q1 += u * u;
        s2 += w2; q2 += w2 * w2;
    }
    __shared__ float red[4][4];
    int lane = threadIdx.x & 63, wv = threadIdx.x >> 6;
#pragma unroll
    for (int off = 32; off > 0; off >>= 1) {
        s1 += __shfl_down(s1, off);
        q1 += __shfl_down(q1, off);
        s2 += __shfl_down(s2, off);
        q2 += __shfl_down(q2, off);
    }
    if (lane == 0) { red[wv][0] = s1; red[wv][1] = q1; red[wv][2] = s2; red[wv][3] = q2; }
    __syncthreads();
    if (threadIdx.x == 0) {
        float S1 = 0, Q1 = 0, S2 = 0, Q2 = 0;
#pragma unroll
        for (int i = 0; i < 4; i++) { S1 += red[i][0]; Q1 += red[i][1]; S2 += red[i][2]; Q2 += red[i][3]; }
        float m1 = S1 * (1.f / D_), m2 = S2 * (1.f / D_);
        float v1 = Q1 * (1.f / D_) - m1 * m1;
        float v2 = Q2 * (1.f / D_) - m2 * m2;
        int m = b * S_ + t;
        mu[m] = m1;           rstd[m] = rsqrtf(v1 + EPS_);
        mu[m + SHIFT_] = m2;  rstd[m + SHIFT_] = rsqrtf(v2 + EPS_);
    }
}

// ---------------- FALLBACK: fp32 fused projection (round-1, proven) --------
__global__ __launch_bounds__(256) void k_proj_fp32(
    const float* __restrict__ x, const float* __restrict__ keyw,
    const float* __restrict__ valw, const float* __restrict__ g,
    const float* __restrict__ lnw, const float* __restrict__ lnb,
    const float* __restrict__ tf, const float* __restrict__ mu,
    const float* __restrict__ rstd, float* __restrict__ wkv) {
    __shared__ float smem[64 * 132];
    float* As = smem;
    float* Bs = smem + 64 * 36;

    int m0 = blockIdx.x * 64;
    int b = m0 >> 12;
    int t0 = m0 & 4095;
    int t2 = (t0 + SHIFT_) & 4095;
    const float* xa_base = x + ((size_t)(b * S_ + t0)) * D_;
    const float* xb_base = x + ((size_t)(b * S_ + t2)) * D_;

    int tid = threadIdx.x;
    int ty = tid >> 4, tx = tid & 15;
    int tokA = tid >> 3;
    int cA = (tid & 7) * 4;

    float mu0 = mu[m0 + tokA],      rs0 = rstd[m0 + tokA];
    float mu1 = mu[m0 + tokA + 32], rs1 = rstd[m0 + tokA + 32];

    int nB = tid >> 1;
    int halfB = tid & 1;
    const float* wrow = (nB < 64) ? (keyw + (size_t)nB * D_)
                                  : (valw + (size_t)(nB - 64) * D_);

    float acc[4][8];
#pragma unroll
    for (int i = 0; i < 4; i++)
#pragma unroll
        for (int j = 0; j < 8; j++) acc[i][j] = 0.f;

    for (int kk0 = 0; kk0 < D_; kk0 += 32) {
        float4 gg = *(const float4*)(g + kk0 + cA);
        float4 lw = *(const float4*)(lnw + kk0 + cA);
        float4 lb = *(const float4*)(lnb + kk0 + cA);
        float gv[4] = {gg.x, gg.y, gg.z, gg.w};
        float lwv[4] = {lw.x, lw.y, lw.z, lw.w};
        float lbv[4] = {lb.x, lb.y, lb.z, lb.w};
#pragma unroll
        for (int r = 0; r < 2; r++) {
            int tok = tokA + r * 32;
            float4 xa = *(const float4*)(xa_base + (size_t)tok * D_ + kk0 + cA);
            float4 xb = *(const float4*)(xb_base + (size_t)tok * D_ + kk0 + cA);
            float xav[4] = {xa.x, xa.y, xa.z, xa.w};
            float xbv[4] = {xb.x, xb.y, xb.z, xb.w};
            float m_ = r ? mu1 : mu0;
            float rs_ = r ? rs1 : rs0;
#pragma unroll
            for (int j = 0; j < 4; j++) {
                float xs = gv[j] * xbv[j] + (1.f - gv[j]) * xav[j];
                As[tok * 36 + cA + j] = (xs - m_) * rs_ * lwv[j] + lbv[j];
            }
        }
#pragma unroll
        for (int cc = 0; cc < 16; cc += 4) {
            int kk = halfB * 16 + cc;
            float4 wv4 = *(const float4*)(wrow + kk0 + kk);
            Bs[(kk + 0) * 132 + nB] = wv4.x;
            Bs[(kk + 1) * 132 + nB] = wv4.y;
            Bs[(kk + 2) * 132 + nB] = wv4.z;
            Bs[(kk + 3) * 132 + nB] = wv4.w;
        }
        __syncthreads();
#pragma unroll
        for (int kk = 0; kk < 32; kk++) {
            float a0 = As[(ty * 4 + 0) * 36 + kk];
            float a1 = As[(ty * 4 + 1) * 36 + kk];
            float a2 = As[(ty * 4 + 2) * 36 + kk];
            float a3 = As[(ty * 4 + 3) * 36 + kk];
            float bvv[8];
#pragma unroll
            for (int j = 0; j < 8; j++) bvv[j] = Bs[kk * 132 + tx * 8 + j];
#pragma unroll
            for (int j = 0; j < 8; j++) {
                acc[0][j] = fmaf(a0, bvv[j], acc[0][j]);
                acc[1][j] = fmaf(a1, bvv[j], acc[1][j]);
                acc[2][j] = fmaf(a2, bvv[j], acc[2][j]);
                acc[3][j] = fmaf(a3, bvv[j], acc[3][j]);
            }
        }
        __syncthreads();
    }
#pragma unroll
    for (int i = 0; i < 4; i++)
#pragma unroll
        for (int j = 0; j < 8; j++)
            smem[(ty * 4 + i) * 132 + tx * 8 + j] = acc[i][j];
    __syncthreads();
    {
        int tok = tid >> 2;
        int n0 = (tid & 3) * 16;
        float* orow = wkv + ((size_t)(m0 + tok)) * N_ + n0;
#pragma unroll
        for (int jj = 0; jj < 16; jj++) {
            int n = n0 + jj;
            float kv = smem[tok * 132 + n];
            float vv = smem[tok * 132 + 64 + n];
            orow[jj] = __expf(-__expf(tf[n]) * kv) * vv;
        }
    }
}

// ---------------- scan: per-chunk local -> carries --------------------------
__global__ __launch_bounds__(64) void k_chunk(const float* __restrict__ wkv,
                                              const float* __restrict__ tdec,
                                              float* __restrict__ Acar) {
    int idx = blockIdx.x;
    int n = threadIdx.x;
    float w = expf(tdec[n]);
    const float* p = wkv + (size_t)idx * (LCH * N_) + n;
    float s = 0.f;
#pragma unroll
    for (int i = 0; i < LCH; i++) s = s * w + p[i * N_];
    Acar[idx * N_ + n] = s;
}

// ---------------- scan: carries across chunks; write last_states -----------
__global__ __launch_bounds__(64) void k_carry(const float* __restrict__ Acar,
                                              const float* __restrict__ tdec,
                                              float* __restrict__ Cin,
                                              float* __restrict__ last) {
    int b = blockIdx.x;
    int n = threadIdx.x;
    float wL = expf(tdec[n] * (float)LCH);
    float c = 0.f;
#pragma unroll 16
    for (int ch = 0; ch < CCH; ch++) {
        Cin[(b * CCH + ch) * N_ + n] = c;
        c = c * wL + Acar[(b * CCH + ch) * N_ + n];
    }
    last[b * N_ + n] = c;
}

// ---------------- scan: rescan with carry-in -> bf16 states -----------------
__global__ __launch_bounds__(64) void k_rescan(const float* __restrict__ wkv,
                                               const float* __restrict__ Cin,
                                               const float* __restrict__ tdec,
                                               short* __restrict__ st) {
    int idx = blockIdx.x;
    int n = threadIdx.x;
    float w = expf(tdec[n]);
    float s = Cin[idx * N_ + n];
    const float* p = wkv + (size_t)idx * (LCH * N_) + n;
    short* q = st + (size_t)idx * (LCH * N_) + n;
#pragma unroll
    for (int i = 0; i < LCH; i++) { s = s * w + p[i * N_]; q[i * N_] = f2bf(s); }
}

// ---------------- output projection: MFMA, direct-global fragments ----------
// out[m][d] = sum_n st[m][n] * ow[d][n];  per block: 64 m x 128 d, K=64
__global__ __launch_bounds__(256) void k_out_mx(const short* __restrict__ st,
                                                const short* __restrict__ owbf,
                                                float* __restrict__ out) {
    int tid = threadIdx.x, wid = tid >> 6, lane = tid & 63;
    int wm = wid >> 1, wn = wid & 1;
    int quad = lane >> 4, l15 = lane & 15;
    int m0 = (blockIdx.x >> 3) * 64;
    int d0 = (blockIdx.x & 7) * 128;
    const short* ab = st + ((size_t)(m0 + wm * 32 + l15)) * N_ + quad * 8;
    const short* bb = owbf + ((size_t)(d0 + wn * 64 + l15)) * N_ + quad * 8;
    v4f acc[2][4];
#pragma unroll
    for (int i = 0; i < 2; i++)
#pragma unroll
        for (int j = 0; j < 4; j++) acc[i][j] = (v4f)0.f;
#pragma unroll
    for (int ks = 0; ks < 2; ks++) {
        v8s a0 = *(const v8s*)(ab + ks * 32);
        v8s a1 = *(const v8s*)(ab + 16 * N_ + ks * 32);
        v8s b0 = *(const v8s*)(bb + ks * 32);
        v8s b1 = *(const v8s*)(bb + 16 * N_ + ks * 32);
        v8s b2 = *(const v8s*)(bb + 32 * N_ + ks * 32);
        v8s b3 = *(const v8s*)(bb + 48 * N_ + ks * 32);
        acc[0][0] = __builtin_amdgcn_mfma_f32_16x16x32_bf16(a0, b0, acc[0][0], 0, 0, 0);
        acc[0][1] = __builtin_amdgcn_mfma_f32_16x16x32_bf16(a0, b1, acc[0][1], 0, 0, 0);
        acc[0][2] = __builtin_amdgcn_mfma_f32_16x16x32_bf16(a0, b2, acc[0][2], 0, 0, 0);
        acc[0][3] = __builtin_amdgcn_mfma_f32_16x16x32_bf16(a0, b3, acc[0][3], 0, 0, 0);
        acc[1][0] = __builtin_amdgcn_mfma_f32_16x16x32_bf16(a1, b0, acc[1][0], 0, 0, 0);
        acc[1][1] = __builtin_amdgcn_mfma_f32_16x16x32_bf16(a1, b1, acc[1][1], 0, 0, 0);
        acc[1][2] = __builtin_amdgcn_mfma_f32_16x16x32_bf16(a1, b2, acc[1][2], 0, 0, 0);
        acc[1][3] = __builtin_amdgcn_mfma_f32_16x16x32_bf16(a1, b3, acc[1][3], 0, 0, 0);
    }
#pragma unroll
    for (int i = 0; i < 2; i++)
#pragma unroll
        for (int j = 0; j < 4; j++) {
            int r0 = m0 + wm * 32 + i * 16 + quad * 4;
            int col = d0 + wn * 64 + j * 16 + l15;
            float* p = out + (size_t)r0 * D_ + col;
            p[0]          = acc[i][j][0];
            p[(size_t)D_] = acc[i][j][1];
            p[(size_t)2 * D_] = acc[i][j][2];
            p[(size_t)3 * D_] = acc[i][j][3];
        }
}

extern "C" void kernel_launch(void* const* d_in, const int* in_sizes, int n_in,
                              void* d_out, int out_size, void* d_ws, size_t ws_size,
                              hipStream_t stream) {
    const float* x    = (const float*)d_in[0];
    const float* tdec = (const float*)d_in[1];
    const float* tf   = (const float*)d_in[2];
    const float* keyw = (const float*)d_in[3];
    const float* valw = (const float*)d_in[4];
    const float* ow   = (const float*)d_in[5];
    const float* tsg  = (const float*)d_in[6];
    const float* lnw  = (const float*)d_in[7];
    const float* lnb  = (const float*)d_in[8];
    float* out = (float*)d_out;
    float* ws  = (float*)d_ws;

    // workspace layout (float offsets)
    float* g     = ws;                        // 1024
    float* etf   = g + 1024;                  // 64
    short* wbf   = (short*)(etf + 64);        // 131072 shorts = 65536 floats
    short* owbf  = (short*)(ws + 66624);      // 65536 shorts = 32768 floats
    float* mu    = ws + 99392;                // 32768
    float* rstd  = mu + 32768;                // 32768
    float* wkv   = rstd + 32768;              // 2097152
    float* Acar  = wkv + 2097152;             // 65536
    float* Cin   = Acar + 65536;              // 65536
    short* stbf  = (short*)(Cin + 65536);     // 2097152 shorts = 1048576 floats
    short* xnorm = (short*)(ws + 3441728);    // 33554432 shorts = 16777216 floats
    const size_t NEED_PRIMARY = (size_t)(3441728 + 16777216) * 4;  // ~80.9 MB

    k_conv<<<773, 256, 0, stream>>>(keyw, valw, ow, tf, tsg, wbf, owbf, etf, g);

    if (ws_size >= NEED_PRIMARY) {
        k_stats_fused<<<B_ * (S_ / 2), 256, 0, stream>>>(x, g, lnw, lnb, xnorm);
        k_proj_mx<<<MTOT / 64, 256, 0, stream>>>(xnorm, wbf, etf, wkv);
    } else {
        k_stats_mu<<<B_ * (S_ / 2), 256, 0, stream>>>(x, g, mu, rstd);
        k_proj_fp32<<<MTOT / 64, 256, 0, stream>>>(x, keyw, valw, g, lnw, lnb, tf, mu, rstd, wkv);
    }
    k_chunk <<<B_ * CCH, 64, 0, stream>>>(wkv, tdec, Acar);
    k_carry <<<B_, 64, 0, stream>>>(Acar, tdec, Cin, out + (size_t)MTOT * D_);
    k_rescan<<<B_ * CCH, 64, 0, stream>>>(wkv, Cin, tdec, stbf);
    k_out_mx<<<(MTOT / 64) * 8, 256, 0, stream>>>(stbf, owbf, out);
}

// Round 3
// 320.553 us; speedup vs baseline: 1.3441x; 1.0046x over previous
//
#include <hip/hip_runtime.h>
#include <math.h>

#define B_ 8
#define S_ 4096
#define D_ 1024
#define N_ 64
#define SHIFT_ 2048
#define LCH 32
#define CCH 128            // S_/LCH
#define MTOT (B_*S_)
#define EPS_ 1e-5f

typedef __attribute__((ext_vector_type(8))) short v8s;
typedef __attribute__((ext_vector_type(4))) float v4f;

static __device__ __forceinline__ short f2bf(float f) {
    // round-to-nearest-even fp32 -> bf16
    unsigned int u = __float_as_uint(f);
    u += 0x7fffu + ((u >> 16) & 1u);
    return (short)(u >> 16);
}

// ---------------- k_conv: weights->bf16, exp(tf), sigmoid(gates) ----------
__global__ __launch_bounds__(256) void k_conv(
    const float* __restrict__ keyw, const float* __restrict__ valw,
    const float* __restrict__ ow, const float* __restrict__ tf,
    const float* __restrict__ tsg,
    short* __restrict__ wbf, short* __restrict__ owbf,
    float* __restrict__ etf, float* __restrict__ g) {
    int i = blockIdx.x * 256 + threadIdx.x;
    if (i < 65536)          wbf[i] = f2bf(keyw[i]);
    else if (i < 131072)    wbf[i] = f2bf(valw[i - 65536]);
    else if (i < 196608)    owbf[i - 131072] = f2bf(ow[i - 131072]);
    else if (i < 196672)    etf[i - 196608] = __expf(tf[i - 196608]);
    else if (i < 197696) {
        int j = i - 196672;
        g[j] = 1.0f / (1.0f + __expf(-tsg[j]));
    }
}

// ---------------- PRIMARY: shift + full LN -> bf16 x_norm ------------------
__global__ __launch_bounds__(256) void k_stats_fused(
    const float* __restrict__ x, const float* __restrict__ g,
    const float* __restrict__ lnw, const float* __restrict__ lnb,
    short* __restrict__ xn) {
    int b = blockIdx.x >> 11;
    int t = blockIdx.x & 2047;
    const float* rowa = x + ((size_t)(b * S_ + t)) * D_;
    const float* rowb = rowa + (size_t)SHIFT_ * D_;
    int c = threadIdx.x * 4;
    float4 xa = *(const float4*)(rowa + c);
    float4 xb = *(const float4*)(rowb + c);
    float4 gg = *(const float4*)(g + c);
    float av[4] = {xa.x, xa.y, xa.z, xa.w};
    float bv[4] = {xb.x, xb.y, xb.z, xb.w};
    float gv[4] = {gg.x, gg.y, gg.z, gg.w};
    float u[4], w2[4];
    float s1 = 0.f, q1 = 0.f, s2 = 0.f, q2 = 0.f;
#pragma unroll
    for (int j = 0; j < 4; j++) {
        u[j]  = gv[j] * bv[j] + (1.f - gv[j]) * av[j];   // token t
        w2[j] = gv[j] * av[j] + (1.f - gv[j]) * bv[j];   // token t+2048
        s1 += u[j];  q1 += u[j] * u[j];
        s2 += w2[j]; q2 += w2[j] * w2[j];
    }
    __shared__ float red[4][4];
    int lane = threadIdx.x & 63, wv = threadIdx.x >> 6;
#pragma unroll
    for (int off = 32; off > 0; off >>= 1) {
        s1 += __shfl_down(s1, off);
        q1 += __shfl_down(q1, off);
        s2 += __shfl_down(s2, off);
        q2 += __shfl_down(q2, off);
    }
    if (lane == 0) { red[wv][0] = s1; red[wv][1] = q1; red[wv][2] = s2; red[wv][3] = q2; }
    __syncthreads();
    float S1 = red[0][0] + red[1][0] + red[2][0] + red[3][0];
    float Q1 = red[0][1] + red[1][1] + red[2][1] + red[3][1];
    float S2 = red[0][2] + red[1][2] + red[2][2] + red[3][2];
    float Q2 = red[0][3] + red[1][3] + red[2][3] + red[3][3];
    float m1 = S1 * (1.f / D_), m2 = S2 * (1.f / D_);
    float rs1 = rsqrtf(Q1 * (1.f / D_) - m1 * m1 + EPS_);
    float rs2 = rsqrtf(Q2 * (1.f / D_) - m2 * m2 + EPS_);
    float4 lw = *(const float4*)(lnw + c);
    float4 lb = *(const float4*)(lnb + c);
    float lwv[4] = {lw.x, lw.y, lw.z, lw.w};
    float lbv[4] = {lb.x, lb.y, lb.z, lb.w};
    short o1[4], o2[4];
#pragma unroll
    for (int j = 0; j < 4; j++) {
        o1[j] = f2bf((u[j]  - m1) * rs1 * lwv[j] + lbv[j]);
        o2[j] = f2bf((w2[j] - m2) * rs2 * lwv[j] + lbv[j]);
    }
    short* d1 = xn + ((size_t)(b * S_ + t)) * D_ + c;
    short* d2 = d1 + (size_t)SHIFT_ * D_;
    *(short4*)d1 = make_short4(o1[0], o1[1], o1[2], o1[3]);
    *(short4*)d2 = make_short4(o2[0], o2[1], o2[2], o2[3]);
}

// ---------------- PRIMARY: MFMA K/V projection + wkv epilogue --------------
// C[64 tok][128 outs] = xnorm(64x1024) @ wbf^T ; no LDS in K-loop.
__global__ __launch_bounds__(256) void k_proj_mx(
    const short* __restrict__ xn, const short* __restrict__ wbf,
    const float* __restrict__ etf, float* __restrict__ wkv) {
    __shared__ float C[64 * 132];   // epilogue only (33.8 KB)
    int tid = threadIdx.x, wid = tid >> 6, lane = tid & 63;
    int wm = wid >> 1, wn = wid & 1;
    int quad = lane >> 4, l15 = lane & 15;
    int m0 = blockIdx.x * 64;
    const short* ab = xn + ((size_t)(m0 + wm * 32 + l15)) * D_ + quad * 8;
    const short* bb = wbf + ((size_t)(wn * 64 + l15)) * D_ + quad * 8;
    v4f acc[2][4];
#pragma unroll
    for (int i = 0; i < 2; i++)
#pragma unroll
        for (int j = 0; j < 4; j++) acc[i][j] = (v4f)0.f;

#pragma unroll 4
    for (int k0 = 0; k0 < D_; k0 += 32) {
        v8s a0 = *(const v8s*)(ab + k0);
        v8s a1 = *(const v8s*)(ab + (size_t)16 * D_ + k0);
        v8s b0 = *(const v8s*)(bb + k0);
        v8s b1 = *(const v8s*)(bb + (size_t)16 * D_ + k0);
        v8s b2 = *(const v8s*)(bb + (size_t)32 * D_ + k0);
        v8s b3 = *(const v8s*)(bb + (size_t)48 * D_ + k0);
        acc[0][0] = __builtin_amdgcn_mfma_f32_16x16x32_bf16(a0, b0, acc[0][0], 0, 0, 0);
        acc[0][1] = __builtin_amdgcn_mfma_f32_16x16x32_bf16(a0, b1, acc[0][1], 0, 0, 0);
        acc[0][2] = __builtin_amdgcn_mfma_f32_16x16x32_bf16(a0, b2, acc[0][2], 0, 0, 0);
        acc[0][3] = __builtin_amdgcn_mfma_f32_16x16x32_bf16(a0, b3, acc[0][3], 0, 0, 0);
        acc[1][0] = __builtin_amdgcn_mfma_f32_16x16x32_bf16(a1, b0, acc[1][0], 0, 0, 0);
        acc[1][1] = __builtin_amdgcn_mfma_f32_16x16x32_bf16(a1, b1, acc[1][1], 0, 0, 0);
        acc[1][2] = __builtin_amdgcn_mfma_f32_16x16x32_bf16(a1, b2, acc[1][2], 0, 0, 0);
        acc[1][3] = __builtin_amdgcn_mfma_f32_16x16x32_bf16(a1, b3, acc[1][3], 0, 0, 0);
    }
    // C/D layout: col = lane&15, row = quad*4 + reg
#pragma unroll
    for (int i = 0; i < 2; i++)
#pragma unroll
        for (int j = 0; j < 4; j++)
#pragma unroll
            for (int r = 0; r < 4; r++)
                C[(wm * 32 + i * 16 + quad * 4 + r) * 132 + wn * 64 + j * 16 + l15] = acc[i][j][r];
    __syncthreads();
    int tok = tid >> 2, n0 = (tid & 3) * 16;
    float* orow = wkv + ((size_t)(m0 + tok)) * N_ + n0;
#pragma unroll
    for (int jj = 0; jj < 16; jj += 4) {
        float4 o;
        float* pk = &C[tok * 132 + n0 + jj];
        float* pv = &C[tok * 132 + 64 + n0 + jj];
        o.x = __expf(-etf[n0 + jj + 0] * pk[0]) * pv[0];
        o.y = __expf(-etf[n0 + jj + 1] * pk[1]) * pv[1];
        o.z = __expf(-etf[n0 + jj + 2] * pk[2]) * pv[2];
        o.w = __expf(-etf[n0 + jj + 3] * pk[3]) * pv[3];
        *(float4*)(orow + jj) = o;
    }
}

// ---------------- FALLBACK: LN stats only ----------------------------------
__global__ __launch_bounds__(256) void k_stats_mu(const float* __restrict__ x,
                                                  const float* __restrict__ g,
                                                  float* __restrict__ mu,
                                                  float* __restrict__ rstd) {
    int b = blockIdx.x >> 11;
    int t = blockIdx.x & 2047;
    const float* rowa = x + ((size_t)(b * S_ + t)) * D_;
    const float* rowb = rowa + (size_t)SHIFT_ * D_;
    int c = threadIdx.x * 4;
    float4 xa = *(const float4*)(rowa + c);
    float4 xb = *(const float4*)(rowb + c);
    float4 gg = *(const float4*)(g + c);
    float av[4] = {xa.x, xa.y, xa.z, xa.w};
    float bv[4] = {xb.x, xb.y, xb.z, xb.w};
    float gv[4] = {gg.x, gg.y, gg.z, gg.w};
    float s1 = 0.f, q1 = 0.f, s2 = 0.f, q2 = 0.f;
#pragma unroll
    for (int j = 0; j < 4; j++) {
        float u  = gv[j] * bv[j] + (1.f - gv[j]) * av[j];
        float w2 = gv[j] * av[j] + (1.f - gv[j]) * bv[j];
        s1 += u;  q1 += u * u;
        s2 += w2; q2 += w2 * w2;
    }
    __shared__ float red[4][4];
    int lane = threadIdx.x & 63, wv = threadIdx.x >> 6;
#pragma unroll
    for (int off = 32; off > 0; off >>= 1) {
        s1 += __shfl_down(s1, off);
        q1 += __shfl_down(q1, off);
        s2 += __shfl_down(s2, off);
        q2 += __shfl_down(q2, off);
    }
    if (lane == 0) { red[wv][0] = s1; red[wv][1] = q1; red[wv][2] = s2; red[wv][3] = q2; }
    __syncthreads();
    if (threadIdx.x == 0) {
        float S1 = 0, Q1 = 0, S2 = 0, Q2 = 0;
#pragma unroll
        for (int i = 0; i < 4; i++) { S1 += red[i][0]; Q1 += red[i][1]; S2 += red[i][2]; Q2 += red[i][3]; }
        float m1 = S1 * (1.f / D_), m2 = S2 * (1.f / D_);
        float v1 = Q1 * (1.f / D_) - m1 * m1;
        float v2 = Q2 * (1.f / D_) - m2 * m2;
        int m = b * S_ + t;
        mu[m] = m1;           rstd[m] = rsqrtf(v1 + EPS_);
        mu[m + SHIFT_] = m2;  rstd[m + SHIFT_] = rsqrtf(v2 + EPS_);
    }
}

// ---------------- FALLBACK: fp32 fused projection (round-1, proven) --------
__global__ __launch_bounds__(256) void k_proj_fp32(
    const float* __restrict__ x, const float* __restrict__ keyw,
    const float* __restrict__ valw, const float* __restrict__ g,
    const float* __restrict__ lnw, const float* __restrict__ lnb,
    const float* __restrict__ tf, const float* __restrict__ mu,
    const float* __restrict__ rstd, float* __restrict__ wkv) {
    __shared__ float smem[64 * 132];
    float* As = smem;
    float* Bs = smem + 64 * 36;

    int m0 = blockIdx.x * 64;
    int b = m0 >> 12;
    int t0 = m0 & 4095;
    int t2 = (t0 + SHIFT_) & 4095;
    const float* xa_base = x + ((size_t)(b * S_ + t0)) * D_;
    const float* xb_base = x + ((size_t)(b * S_ + t2)) * D_;

    int tid = threadIdx.x;
    int ty = tid >> 4, tx = tid & 15;
    int tokA = tid >> 3;
    int cA = (tid & 7) * 4;

    float mu0 = mu[m0 + tokA],      rs0 = rstd[m0 + tokA];
    float mu1 = mu[m0 + tokA + 32], rs1 = rstd[m0 + tokA + 32];

    int nB = tid >> 1;
    int halfB = tid & 1;
    const float* wrow = (nB < 64) ? (keyw + (size_t)nB * D_)
                                  : (valw + (size_t)(nB - 64) * D_);

    float acc[4][8];
#pragma unroll
    for (int i = 0; i < 4; i++)
#pragma unroll
        for (int j = 0; j < 8; j++) acc[i][j] = 0.f;

    for (int kk0 = 0; kk0 < D_; kk0 += 32) {
        float4 gg = *(const float4*)(g + kk0 + cA);
        float4 lw = *(const float4*)(lnw + kk0 + cA);
        float4 lb = *(const float4*)(lnb + kk0 + cA);
        float gv[4] = {gg.x, gg.y, gg.z, gg.w};
        float lwv[4] = {lw.x, lw.y, lw.z, lw.w};
        float lbv[4] = {lb.x, lb.y, lb.z, lb.w};
#pragma unroll
        for (int r = 0; r < 2; r++) {
            int tok = tokA + r * 32;
            float4 xa = *(const float4*)(xa_base + (size_t)tok * D_ + kk0 + cA);
            float4 xb = *(const float4*)(xb_base + (size_t)tok * D_ + kk0 + cA);
            float xav[4] = {xa.x, xa.y, xa.z, xa.w};
            float xbv[4] = {xb.x, xb.y, xb.z, xb.w};
            float m_ = r ? mu1 : mu0;
            float rs_ = r ? rs1 : rs0;
#pragma unroll
            for (int j = 0; j < 4; j++) {
                float xs = gv[j] * xbv[j] + (1.f - gv[j]) * xav[j];
                As[tok * 36 + cA + j] = (xs - m_) * rs_ * lwv[j] + lbv[j];
            }
        }
#pragma unroll
        for (int cc = 0; cc < 16; cc += 4) {
            int kk = halfB * 16 + cc;
            float4 wv4 = *(const float4*)(wrow + kk0 + kk);
            Bs[(kk + 0) * 132 + nB] = wv4.x;
            Bs[(kk + 1) * 132 + nB] = wv4.y;
            Bs[(kk + 2) * 132 + nB] = wv4.z;
            Bs[(kk + 3) * 132 + nB] = wv4.w;
        }
        __syncthreads();
#pragma unroll
        for (int kk = 0; kk < 32; kk++) {
            float a0 = As[(ty * 4 + 0) * 36 + kk];
            float a1 = As[(ty * 4 + 1) * 36 + kk];
            float a2 = As[(ty * 4 + 2) * 36 + kk];
            float a3 = As[(ty * 4 + 3) * 36 + kk];
            float bvv[8];
#pragma unroll
            for (int j = 0; j < 8; j++) bvv[j] = Bs[kk * 132 + tx * 8 + j];
#pragma unroll
            for (int j = 0; j < 8; j++) {
                acc[0][j] = fmaf(a0, bvv[j], acc[0][j]);
                acc[1][j] = fmaf(a1, bvv[j], acc[1][j]);
                acc[2][j] = fmaf(a2, bvv[j], acc[2][j]);
                acc[3][j] = fmaf(a3, bvv[j], acc[3][j]);
            }
        }
        __syncthreads();
    }
#pragma unroll
    for (int i = 0; i < 4; i++)
#pragma unroll
        for (int j = 0; j < 8; j++)
            smem[(ty * 4 + i) * 132 + tx * 8 + j] = acc[i][j];
    __syncthreads();
    {
        int tok = tid >> 2;
        int n0 = (tid & 3) * 16;
        float* orow = wkv + ((size_t)(m0 + tok)) * N_ + n0;
#pragma unroll
        for (int jj = 0; jj < 16; jj++) {
            int n = n0 + jj;
            float kv = smem[tok * 132 + n];
            float vv = smem[tok * 132 + 64 + n];
            orow[jj] = __expf(-__expf(tf[n]) * kv) * vv;
        }
    }
}

// ---------------- scan: per-chunk local -> carries --------------------------
__global__ __launch_bounds__(64) void k_chunk(const float* __restrict__ wkv,
                                              const float* __restrict__ tdec,
                                              float* __restrict__ Acar) {
    int idx = blockIdx.x;
    int n = threadIdx.x;
    float w = expf(tdec[n]);
    const float* p = wkv + (size_t)idx * (LCH * N_) + n;
    float s = 0.f;
#pragma unroll
    for (int i = 0; i < LCH; i++) s = s * w + p[i * N_];
    Acar[idx * N_ + n] = s;
}

// ---------------- scan: carries across chunks; write last_states -----------
__global__ __launch_bounds__(64) void k_carry(const float* __restrict__ Acar,
                                              const float* __restrict__ tdec,
                                              float* __restrict__ Cin,
                                              float* __restrict__ last) {
    int b = blockIdx.x;
    int n = threadIdx.x;
    float wL = expf(tdec[n] * (float)LCH);
    float c = 0.f;
#pragma unroll 16
    for (int ch = 0; ch < CCH; ch++) {
        Cin[(b * CCH + ch) * N_ + n] = c;
        c = c * wL + Acar[(b * CCH + ch) * N_ + n];
    }
    last[b * N_ + n] = c;
}

// ---------------- scan: rescan with carry-in -> bf16 states -----------------
__global__ __launch_bounds__(64) void k_rescan(const float* __restrict__ wkv,
                                               const float* __restrict__ Cin,
                                               const float* __restrict__ tdec,
                                               short* __restrict__ st) {
    int idx = blockIdx.x;
    int n = threadIdx.x;
    float w = expf(tdec[n]);
    float s = Cin[idx * N_ + n];
    const float* p = wkv + (size_t)idx * (LCH * N_) + n;
    short* q = st + (size_t)idx * (LCH * N_) + n;
#pragma unroll
    for (int i = 0; i < LCH; i++) { s = s * w + p[i * N_]; q[i * N_] = f2bf(s); }
}

// ---------------- output projection: MFMA + LDS epilogue, coalesced stores --
// out[m][d] = sum_n st[m][n] * ow[d][n];  per block: 64 m x 128 d, K=64
__global__ __launch_bounds__(256) void k_out_mx(const short* __restrict__ st,
                                                const short* __restrict__ owbf,
                                                float* __restrict__ out) {
    __shared__ float C[64 * 132];   // 33.8 KB
    int tid = threadIdx.x, wid = tid >> 6, lane = tid & 63;
    int wm = wid >> 1, wn = wid & 1;
    int quad = lane >> 4, l15 = lane & 15;
    int m0 = (blockIdx.x >> 3) * 64;
    int d0 = (blockIdx.x & 7) * 128;
    const short* ab = st + ((size_t)(m0 + wm * 32 + l15)) * N_ + quad * 8;
    const short* bb = owbf + ((size_t)(d0 + wn * 64 + l15)) * N_ + quad * 8;
    v4f acc[2][4];
#pragma unroll
    for (int i = 0; i < 2; i++)
#pragma unroll
        for (int j = 0; j < 4; j++) acc[i][j] = (v4f)0.f;
#pragma unroll
    for (int ks = 0; ks < 2; ks++) {
        v8s a0 = *(const v8s*)(ab + ks * 32);
        v8s a1 = *(const v8s*)(ab + 16 * N_ + ks * 32);
        v8s b0 = *(const v8s*)(bb + ks * 32);
        v8s b1 = *(const v8s*)(bb + 16 * N_ + ks * 32);
        v8s b2 = *(const v8s*)(bb + 32 * N_ + ks * 32);
        v8s b3 = *(const v8s*)(bb + 48 * N_ + ks * 32);
        acc[0][0] = __builtin_amdgcn_mfma_f32_16x16x32_bf16(a0, b0, acc[0][0], 0, 0, 0);
        acc[0][1] = __builtin_amdgcn_mfma_f32_16x16x32_bf16(a0, b1, acc[0][1], 0, 0, 0);
        acc[0][2] = __builtin_amdgcn_mfma_f32_16x16x32_bf16(a0, b2, acc[0][2], 0, 0, 0);
        acc[0][3] = __builtin_amdgcn_mfma_f32_16x16x32_bf16(a0, b3, acc[0][3], 0, 0, 0);
        acc[1][0] = __builtin_amdgcn_mfma_f32_16x16x32_bf16(a1, b0, acc[1][0], 0, 0, 0);
        acc[1][1] = __builtin_amdgcn_mfma_f32_16x16x32_bf16(a1, b1, acc[1][1], 0, 0, 0);
        acc[1][2] = __builtin_amdgcn_mfma_f32_16x16x32_bf16(a1, b2, acc[1][2], 0, 0, 0);
        acc[1][3] = __builtin_amdgcn_mfma_f32_16x16x32_bf16(a1, b3, acc[1][3], 0, 0, 0);
    }
    // stash C in LDS (same proven layout as k_proj_mx)
#pragma unroll
    for (int i = 0; i < 2; i++)
#pragma unroll
        for (int j = 0; j < 4; j++)
#pragma unroll
            for (int r = 0; r < 4; r++)
                C[(wm * 32 + i * 16 + quad * 4 + r) * 132 + wn * 64 + j * 16 + l15] = acc[i][j][r];
    __syncthreads();
    // coalesced stores: 8 lanes cover one row's 128B segment per instruction
    // thread -> row = rep*32 + (tid>>3), col = (tid&7)*4 + k*32, k=0..3
    int rrow = tid >> 3;
    int ccol = (tid & 7) * 4;
#pragma unroll
    for (int rep = 0; rep < 2; rep++) {
        int row = rep * 32 + rrow;
        float* orow = out + ((size_t)(m0 + row)) * D_ + d0;
        const float* crow = &C[row * 132];
#pragma unroll
        for (int k = 0; k < 4; k++) {
            int col = ccol + k * 32;
            *(float4*)(orow + col) = *(const float4*)(crow + col);
        }
    }
}

extern "C" void kernel_launch(void* const* d_in, const int* in_sizes, int n_in,
                              void* d_out, int out_size, void* d_ws, size_t ws_size,
                              hipStream_t stream) {
    const float* x    = (const float*)d_in[0];
    const float* tdec = (const float*)d_in[1];
    const float* tf   = (const float*)d_in[2];
    const float* keyw = (const float*)d_in[3];
    const float* valw = (const float*)d_in[4];
    const float* ow   = (const float*)d_in[5];
    const float* tsg  = (const float*)d_in[6];
    const float* lnw  = (const float*)d_in[7];
    const float* lnb  = (const float*)d_in[8];
    float* out = (float*)d_out;
    float* ws  = (float*)d_ws;

    // workspace layout (float offsets)
    float* g     = ws;                        // 1024
    float* etf   = g + 1024;                  // 64
    short* wbf   = (short*)(etf + 64);        // 131072 shorts = 65536 floats
    short* owbf  = (short*)(ws + 66624);      // 65536 shorts = 32768 floats
    float* mu    = ws + 99392;                // 32768
    float* rstd  = mu + 32768;                // 32768
    float* wkv   = rstd + 32768;              // 2097152
    float* Acar  = wkv + 2097152;             // 65536
    float* Cin   = Acar + 65536;              // 65536
    short* stbf  = (short*)(Cin + 65536);     // 2097152 shorts = 1048576 floats
    short* xnorm = (short*)(ws + 3441728);    // 33554432 shorts = 16777216 floats
    const size_t NEED_PRIMARY = (size_t)(3441728 + 16777216) * 4;  // ~80.9 MB

    k_conv<<<773, 256, 0, stream>>>(keyw, valw, ow, tf, tsg, wbf, owbf, etf, g);

    if (ws_size >= NEED_PRIMARY) {
        k_stats_fused<<<B_ * (S_ / 2), 256, 0, stream>>>(x, g, lnw, lnb, xnorm);
        k_proj_mx<<<MTOT / 64, 256, 0, stream>>>(xnorm, wbf, etf, wkv);
    } else {
        k_stats_mu<<<B_ * (S_ / 2), 256, 0, stream>>>(x, g, mu, rstd);
        k_proj_fp32<<<MTOT / 64, 256, 0, stream>>>(x, keyw, valw, g, lnw, lnb, tf, mu, rstd, wkv);
    }
    k_chunk <<<B_ * CCH, 64, 0, stream>>>(wkv, tdec, Acar);
    k_carry <<<B_, 64, 0, stream>>>(Acar, tdec, Cin, out + (size_t)MTOT * D_);
    k_rescan<<<B_ * CCH, 64, 0, stream>>>(wkv, Cin, tdec, stbf);
    k_out_mx<<<(MTOT / 64) * 8, 256, 0, stream>>>(stbf, owbf, out);
}